// Round 13
// baseline (332.309 us; speedup 1.0000x reference)
//
#include <hip/hip_runtime.h>

#define NROWS 8192
#define DDIM  256
#define BM    128
#define BN    128
#define BK    64

typedef __attribute__((ext_vector_type(8))) short bf16x8;
typedef __attribute__((ext_vector_type(4))) float f32x4;

// round-to-nearest-even f32 -> bf16 bits (inputs are finite gaussians; no NaN path)
static __device__ __forceinline__ unsigned short f2bf(float f) {
    unsigned u = __float_as_uint(f);
    u += 0x7fff + ((u >> 16) & 1);
    return (unsigned short)(u >> 16);
}

// Pass 1: f32 -> bf16 conversion + per-row sum of squares.
__global__ __launch_bounds__(256) void rbf_prep_kernel(
    const float* __restrict__ x, const float* __restrict__ y,
    unsigned short* __restrict__ xb, unsigned short* __restrict__ yb,
    float* __restrict__ xsq, float* __restrict__ ysq)
{
    const int lane = threadIdx.x & 63;
    const int wid  = threadIdx.x >> 6;
    int row = blockIdx.x * 4 + wid;            // 0..16383
    const float* src; unsigned short* dst; float* sq; int r;
    if (row < NROWS) { src = x; dst = xb; sq = xsq; r = row; }
    else             { src = y; dst = yb; sq = ysq; r = row - NROWS; }

    const float4 v = ((const float4*)(src + (size_t)r * DDIM))[lane];
    ushort4 b;
    b.x = f2bf(v.x); b.y = f2bf(v.y); b.z = f2bf(v.z); b.w = f2bf(v.w);
    ((ushort4*)(dst + (size_t)r * DDIM))[lane] = b;

    float s = v.x * v.x + v.y * v.y + v.z * v.z + v.w * v.w;
    #pragma unroll
    for (int o = 32; o > 0; o >>= 1) s += __shfl_down(s, o);
    if (lane == 0) sq[r] = s;
}

// Pass 2: R11 structure (128x128, 4 waves 2x2, single-buffer, T2 swizzle,
// nt stores) + two occupancy/locality levers:
//  - __launch_bounds__(256,4): cap VGPR at 128 -> 4 blocks/CU (was ~2-3).
//    Blocks are phase-locked (equal duration, co-launch); overlap of
//    store/MFMA/stage phases comes from block concurrency, so +blocks =
//    +store-stream continuity. (serial-sum 253k cyc/CU vs measured 199k
//    => overlap factor only 1.27 today)
//  - T1 XCD-chunked swizzle (4096%8==0 -> bijective simple form): 512
//    consecutive tiles per XCD = 8 A-panel rows reused within one L2;
//    all of Y (4MiB bf16) fits a single XCD L2 -> stage loads ~L2-hit.
__global__ __launch_bounds__(256, 4) void rbf_gemm_kernel(
    const unsigned short* __restrict__ A,   // 8192 x 256 bf16 (X)
    const unsigned short* __restrict__ B,   // 8192 x 256 bf16 (Y)
    const float* __restrict__ xsq, const float* __restrict__ ysq,
    float* __restrict__ out)
{
    __shared__ unsigned short As[BM * BK];
    __shared__ unsigned short Bs[BN * BK];

    const int t    = threadIdx.x;
    const int lane = t & 63;
    const int wid  = t >> 6;
    const int wr   = wid >> 1;          // wave row (0..1) -> 64-row slab of X
    const int wc   = wid & 1;           // wave col (0..1) -> 64-col slab of Y
    // XCD-aware bijective swizzle: nwg=4096, 8 XCDs, 512 tiles/XCD chunk
    const int swz  = (blockIdx.x & 7) * 512 + (blockIdx.x >> 3);
    const int brow = (swz >> 6) * BM;
    const int bcol = (swz & 63) * BN;

    f32x4 acc[4][4] = {};               // [m][n] transposed 16x16 fragments

    const int rr = lane & 15;           // row within fragment (both operands)
    const int kq = lane >> 4;           // k-quarter
    const int cl = lane & 15;
    const int rq = lane >> 4;

    for (int kt = 0; kt < DDIM; kt += BK) {
        #pragma unroll
        for (int i = 0; i < 4; ++i) {
            const int idx = (i * 256 + t) * 8;      // element index in tile (16B-chunk aligned)
            const int r   = idx >> 6;               // tile row
            const int c   = idx & 63;               // linear chunk col (elements)
            const int cs  = c ^ ((r & 7) << 3);     // inverse-swizzled SOURCE col
            __builtin_amdgcn_global_load_lds(
                (const __attribute__((address_space(1))) unsigned int*)(A + (size_t)(brow + r) * DDIM + kt + cs),
                (__attribute__((address_space(3))) unsigned int*)(As + idx), 16, 0, 0);
            __builtin_amdgcn_global_load_lds(
                (const __attribute__((address_space(1))) unsigned int*)(B + (size_t)(bcol + r) * DDIM + kt + cs),
                (__attribute__((address_space(3))) unsigned int*)(Bs + idx), 16, 0, 0);
        }
        __syncthreads();

        #pragma unroll
        for (int ks = 0; ks < 2; ++ks) {
            bf16x8 a[4], b[4];
            const int ko = ks * 32 + kq * 8;        // logical k-offset (elements)
            const int sw = (rr & 7) << 3;           // row's swizzle bits
            #pragma unroll
            for (int m = 0; m < 4; ++m)
                a[m] = *(const bf16x8*)(As + (wr * 64 + m * 16 + rr) * BK + (ko ^ sw));
            #pragma unroll
            for (int n = 0; n < 4; ++n)
                b[n] = *(const bf16x8*)(Bs + (wc * 64 + n * 16 + rr) * BK + (ko ^ sw));
            #pragma unroll
            for (int m = 0; m < 4; ++m)
                #pragma unroll
                for (int n = 0; n < 4; ++n)
                    acc[m][n] = __builtin_amdgcn_mfma_f32_16x16x32_bf16(b[n], a[m], acc[m][n], 0, 0, 0);
        }
        __syncthreads();
    }

    // epilogue: swapped-operand fragment => lane's X row = lane&15,
    // Y cols = (lane>>4)*4 + {0..3} -> nontemporal f32x4 stores
    #pragma unroll
    for (int m = 0; m < 4; ++m) {
        const int row = brow + wr * 64 + m * 16 + cl;
        const float xsv = xsq[row];
        float* orow = out + (size_t)row * NROWS;
        #pragma unroll
        for (int n = 0; n < 4; ++n) {
            const int col = bcol + wc * 64 + n * 16 + rq * 4;
            const float4 ysv = *(const float4*)(ysq + col);
            f32x4 o;
            o[0] = __expf(-fmaxf(xsv + ysv.x - 2.0f * acc[m][n][0], 0.0f));
            o[1] = __expf(-fmaxf(xsv + ysv.y - 2.0f * acc[m][n][1], 0.0f));
            o[2] = __expf(-fmaxf(xsv + ysv.z - 2.0f * acc[m][n][2], 0.0f));
            o[3] = __expf(-fmaxf(xsv + ysv.w - 2.0f * acc[m][n][3], 0.0f));
            __builtin_nontemporal_store(o, (f32x4*)(orow + col));
        }
    }
}

extern "C" void kernel_launch(void* const* d_in, const int* in_sizes, int n_in,
                              void* d_out, int out_size, void* d_ws, size_t ws_size,
                              hipStream_t stream) {
    const float* x = (const float*)d_in[0];
    const float* y = (const float*)d_in[1];
    float* out = (float*)d_out;

    // ws layout: xb (4 MiB) | yb (4 MiB) | xsq (32 KiB) | ysq (32 KiB)
    unsigned short* xb = (unsigned short*)d_ws;
    unsigned short* yb = xb + (size_t)NROWS * DDIM;
    float* xsq = (float*)(yb + (size_t)NROWS * DDIM);
    float* ysq = xsq + NROWS;

    rbf_prep_kernel<<<dim3((2 * NROWS) / 4), 256, 0, stream>>>(x, y, xb, yb, xsq, ysq);
    rbf_gemm_kernel<<<dim3((NROWS / BM) * (NROWS / BN)), 256, 0, stream>>>(xb, yb, xsq, ysq, out);
}

// Round 14
// 301.537 us; speedup vs baseline: 1.1020x; 1.1020x over previous
//
#include <hip/hip_runtime.h>

#define NROWS 8192
#define DDIM  256
#define BM    128
#define BN    128
#define BK    64

typedef __attribute__((ext_vector_type(8))) short bf16x8;
typedef __attribute__((ext_vector_type(4))) float f32x4;

// round-to-nearest-even f32 -> bf16 bits (inputs are finite gaussians; no NaN path)
static __device__ __forceinline__ unsigned short f2bf(float f) {
    unsigned u = __float_as_uint(f);
    u += 0x7fff + ((u >> 16) & 1);
    return (unsigned short)(u >> 16);
}

// Pass 1: f32 -> bf16 conversion + per-row sum of squares.
__global__ __launch_bounds__(256) void rbf_prep_kernel(
    const float* __restrict__ x, const float* __restrict__ y,
    unsigned short* __restrict__ xb, unsigned short* __restrict__ yb,
    float* __restrict__ xsq, float* __restrict__ ysq)
{
    const int lane = threadIdx.x & 63;
    const int wid  = threadIdx.x >> 6;
    int row = blockIdx.x * 4 + wid;            // 0..16383
    const float* src; unsigned short* dst; float* sq; int r;
    if (row < NROWS) { src = x; dst = xb; sq = xsq; r = row; }
    else             { src = y; dst = yb; sq = ysq; r = row - NROWS; }

    const float4 v = ((const float4*)(src + (size_t)r * DDIM))[lane];
    ushort4 b;
    b.x = f2bf(v.x); b.y = f2bf(v.y); b.z = f2bf(v.z); b.w = f2bf(v.w);
    ((ushort4*)(dst + (size_t)r * DDIM))[lane] = b;

    float s = v.x * v.x + v.y * v.y + v.z * v.z + v.w * v.w;
    #pragma unroll
    for (int o = 32; o > 0; o >>= 1) s += __shfl_down(s, o);
    if (lane == 0) sq[r] = s;
}

// Pass 2: measured-best structure (R11, 302.1us): 128x128 tile, 4 waves 2x2,
// single-buffered 2-barrier K-loop, T2 both-sides XOR swizzle, nt stores,
// 2-D grid (bx-major dispatch shares A-panels in L2).
// Bracketed-out by measurement: dbuf(317), persistence(322), 256x128(335),
// no-LDS reg-direct(322), launch_bounds(256,4)+1D-XCD-swizzle(332 — VGPR cap
// spills acc; 1D swizzle broke bx-major A-panel L2 reuse).
__global__ __launch_bounds__(256) void rbf_gemm_kernel(
    const unsigned short* __restrict__ A,   // 8192 x 256 bf16 (X)
    const unsigned short* __restrict__ B,   // 8192 x 256 bf16 (Y)
    const float* __restrict__ xsq, const float* __restrict__ ysq,
    float* __restrict__ out)
{
    __shared__ unsigned short As[BM * BK];
    __shared__ unsigned short Bs[BN * BK];

    const int t    = threadIdx.x;
    const int lane = t & 63;
    const int wid  = t >> 6;
    const int wr   = wid >> 1;          // wave row (0..1) -> 64-row slab of X
    const int wc   = wid & 1;           // wave col (0..1) -> 64-col slab of Y
    const int brow = blockIdx.y * BM;
    const int bcol = blockIdx.x * BN;

    f32x4 acc[4][4] = {};               // [m][n] transposed 16x16 fragments

    const int rr = lane & 15;           // row within fragment (both operands)
    const int kq = lane >> 4;           // k-quarter
    const int cl = lane & 15;
    const int rq = lane >> 4;

    for (int kt = 0; kt < DDIM; kt += BK) {
        #pragma unroll
        for (int i = 0; i < 4; ++i) {
            const int idx = (i * 256 + t) * 8;      // element index in tile (16B-chunk aligned)
            const int r   = idx >> 6;               // tile row
            const int c   = idx & 63;               // linear chunk col (elements)
            const int cs  = c ^ ((r & 7) << 3);     // inverse-swizzled SOURCE col
            __builtin_amdgcn_global_load_lds(
                (const __attribute__((address_space(1))) unsigned int*)(A + (size_t)(brow + r) * DDIM + kt + cs),
                (__attribute__((address_space(3))) unsigned int*)(As + idx), 16, 0, 0);
            __builtin_amdgcn_global_load_lds(
                (const __attribute__((address_space(1))) unsigned int*)(B + (size_t)(bcol + r) * DDIM + kt + cs),
                (__attribute__((address_space(3))) unsigned int*)(Bs + idx), 16, 0, 0);
        }
        __syncthreads();

        #pragma unroll
        for (int ks = 0; ks < 2; ++ks) {
            bf16x8 a[4], b[4];
            const int ko = ks * 32 + kq * 8;        // logical k-offset (elements)
            const int sw = (rr & 7) << 3;           // row's swizzle bits
            #pragma unroll
            for (int m = 0; m < 4; ++m)
                a[m] = *(const bf16x8*)(As + (wr * 64 + m * 16 + rr) * BK + (ko ^ sw));
            #pragma unroll
            for (int n = 0; n < 4; ++n)
                b[n] = *(const bf16x8*)(Bs + (wc * 64 + n * 16 + rr) * BK + (ko ^ sw));
            #pragma unroll
            for (int m = 0; m < 4; ++m)
                #pragma unroll
                for (int n = 0; n < 4; ++n)
                    acc[m][n] = __builtin_amdgcn_mfma_f32_16x16x32_bf16(b[n], a[m], acc[m][n], 0, 0, 0);
        }
        __syncthreads();
    }

    // epilogue: swapped-operand fragment => lane's X row = lane&15,
    // Y cols = (lane>>4)*4 + {0..3} -> nontemporal f32x4 stores
    #pragma unroll
    for (int m = 0; m < 4; ++m) {
        const int row = brow + wr * 64 + m * 16 + cl;
        const float xsv = xsq[row];
        float* orow = out + (size_t)row * NROWS;
        #pragma unroll
        for (int n = 0; n < 4; ++n) {
            const int col = bcol + wc * 64 + n * 16 + rq * 4;
            const float4 ysv = *(const float4*)(ysq + col);
            f32x4 o;
            o[0] = __expf(-fmaxf(xsv + ysv.x - 2.0f * acc[m][n][0], 0.0f));
            o[1] = __expf(-fmaxf(xsv + ysv.y - 2.0f * acc[m][n][1], 0.0f));
            o[2] = __expf(-fmaxf(xsv + ysv.z - 2.0f * acc[m][n][2], 0.0f));
            o[3] = __expf(-fmaxf(xsv + ysv.w - 2.0f * acc[m][n][3], 0.0f));
            __builtin_nontemporal_store(o, (f32x4*)(orow + col));
        }
    }
}

extern "C" void kernel_launch(void* const* d_in, const int* in_sizes, int n_in,
                              void* d_out, int out_size, void* d_ws, size_t ws_size,
                              hipStream_t stream) {
    const float* x = (const float*)d_in[0];
    const float* y = (const float*)d_in[1];
    float* out = (float*)d_out;

    // ws layout: xb (4 MiB) | yb (4 MiB) | xsq (32 KiB) | ysq (32 KiB)
    unsigned short* xb = (unsigned short*)d_ws;
    unsigned short* yb = xb + (size_t)NROWS * DDIM;
    float* xsq = (float*)(yb + (size_t)NROWS * DDIM);
    float* ysq = xsq + NROWS;

    rbf_prep_kernel<<<dim3((2 * NROWS) / 4), 256, 0, stream>>>(x, y, xb, yb, xsq, ysq);
    rbf_gemm_kernel<<<dim3(NROWS / BN, NROWS / BM), 256, 0, stream>>>(xb, yb, xsq, ysq, out);
}